// Round 8
// baseline (840.710 us; speedup 1.0000x reference)
//
#include <hip/hip_runtime.h>
#include <hip/hip_bf16.h>
#include <hip/hip_fp16.h>

// GCN, bucket-sorted edge list + CHUNKED per-bucket LDS aggregation.
//  - Partition: B2=11 (2048 nodes/bucket, 489 buckets), TILE=8192, padded x4
//    with sentinel 0x80000000; consumers stream pairs as aligned int4.
//  - Aggregation: each bucket split into P=4 edge chunks -> 1956 blocks x 256
//    thr (vs 489x512 before: fixes the 34% occupancy ceiling). Chunk-blocks
//    accumulate in LDS fp32, then flush via coalesced unsafeAtomicAdd into
//    global fp32 accumulators pre-initialized with the fp32 self-loop term.
//  - Gather arrays <= 4MB (per-XCD L2): y16 half2; layer2 split hp01/h2.
//  - Node kernels carry the epilogues (W1/relu/W2; sigmoid+MLP).

constexpr int NT = 256;
constexpr int SCAN_E = 1024;   // fallback scan tile
constexpr int B2 = 11;
constexpr int BN = 1 << B2;    // 2048 nodes / bucket
constexpr int NBMAX = 512;
constexpr int TILE = 8192;     // edges per passA tile
constexpr int P = 4;           // chunks per bucket in agg kernels
constexpr int SENT = (int)0x80000000;

// ================= pass A: bucket histogram =================
__global__ void k_binhist(const int* __restrict__ dst, int* __restrict__ ghist, int E) {
    __shared__ int cnt[NBMAX];
    int t0 = blockIdx.x * TILE;
    for (int l = threadIdx.x; l < NBMAX; l += NT) cnt[l] = 0;
    __syncthreads();
    for (int k = 0; k < TILE / (NT * 4); ++k) {
        int idx = t0 + (k * NT + threadIdx.x) * 4;
        if (idx + 3 < E) {
            int4 d4 = *(const int4*)(dst + idx);
            atomicAdd(&cnt[d4.x >> B2], 1);
            atomicAdd(&cnt[d4.y >> B2], 1);
            atomicAdd(&cnt[d4.z >> B2], 1);
            atomicAdd(&cnt[d4.w >> B2], 1);
        } else {
            for (int j = 0; j < 4; ++j)
                if (idx + j < E) atomicAdd(&cnt[dst[idx + j] >> B2], 1);
        }
    }
    __syncthreads();
    for (int l = threadIdx.x; l < NBMAX; l += NT)
        if (cnt[l]) atomicAdd(&ghist[l], cnt[l]);
}

// ==== scan buckets (pad sizes to x4) + write sentinels into pad gaps ====
__global__ void k_scanbuckets(const int* __restrict__ ghist, int* __restrict__ gbase,
                              int* __restrict__ gcur, int* __restrict__ pairs, int NB) {
    __shared__ int part[NBMAX];
    int tid = threadIdx.x;
    int t = (tid < NB) ? ghist[tid] : 0;
    int p = (t + 3) & ~3;                  // padded size
    part[tid] = p;
    __syncthreads();
    for (int off = 1; off < NBMAX; off <<= 1) {
        int v = (tid >= off) ? part[tid - off] : 0;
        __syncthreads();
        part[tid] += v;
        __syncthreads();
    }
    int excl = part[tid] - p;
    if (tid < NB) {
        gbase[tid] = excl; gcur[tid] = excl;
        for (int e = excl + t; e < part[tid]; ++e) pairs[e] = SENT;
    }
    if (tid == 0) gbase[NB] = part[NBMAX - 1];
}

// ========== pass A scatter: bin packed (src | dlow<<20) by dst>>B2 ==========
__global__ void k_binscatter(const int* __restrict__ src, const int* __restrict__ dst,
                             int* __restrict__ gcur, int* __restrict__ pairs,
                             int E, int NB) {
    __shared__ int cnt[NBMAX], cur[NBMAX], gpos[NBMAX];
    __shared__ int lbase2[NBMAX + 1];
    __shared__ int part[NT];
    __shared__ int lbuf[TILE];
    __shared__ int totalSh;
    int t0 = blockIdx.x * TILE;
    int tid = threadIdx.x;
    for (int l = tid; l < NBMAX; l += NT) cnt[l] = 0;
    __syncthreads();
    // count
    for (int k = 0; k < TILE / (NT * 4); ++k) {
        int idx = t0 + (k * NT + tid) * 4;
        if (idx + 3 < E) {
            int4 d4 = *(const int4*)(dst + idx);
            atomicAdd(&cnt[d4.x >> B2], 1);
            atomicAdd(&cnt[d4.y >> B2], 1);
            atomicAdd(&cnt[d4.z >> B2], 1);
            atomicAdd(&cnt[d4.w >> B2], 1);
        } else {
            for (int j = 0; j < 4; ++j)
                if (idx + j < E) atomicAdd(&cnt[dst[idx + j] >> B2], 1);
        }
    }
    __syncthreads();
    // scan 512 counters with 256 threads (chunk of 2)
    int c0 = cnt[2 * tid], c1 = cnt[2 * tid + 1];
    int t = c0 + c1;
    part[tid] = t;
    __syncthreads();
    for (int off = 1; off < NT; off <<= 1) {
        int v = (tid >= off) ? part[tid - off] : 0;
        __syncthreads();
        part[tid] += v;
        __syncthreads();
    }
    int ex = part[tid] - t;
    lbase2[2 * tid] = ex;          cur[2 * tid] = ex;
    lbase2[2 * tid + 1] = ex + c0; cur[2 * tid + 1] = ex + c0;
    if (tid == NT - 1) { lbase2[NBMAX] = part[NT - 1]; totalSh = part[NT - 1]; }
    __syncthreads();
    // reserve global ranges
    for (int j = tid; j < NBMAX; j += NT)
        if (j < NB && cnt[j]) gpos[j] = atomicAdd(&gcur[j], cnt[j]);
    __syncthreads();
    // place into LDS sorted by bucket
    for (int k = 0; k < TILE / (NT * 4); ++k) {
        int idx = t0 + (k * NT + tid) * 4;
        if (idx + 3 < E) {
            int4 s4 = *(const int4*)(src + idx);
            int4 d4 = *(const int4*)(dst + idx);
            int b, sl;
            b = d4.x >> B2; sl = atomicAdd(&cur[b], 1);
            lbuf[sl] = s4.x | ((d4.x & (BN - 1)) << 20);
            b = d4.y >> B2; sl = atomicAdd(&cur[b], 1);
            lbuf[sl] = s4.y | ((d4.y & (BN - 1)) << 20);
            b = d4.z >> B2; sl = atomicAdd(&cur[b], 1);
            lbuf[sl] = s4.z | ((d4.z & (BN - 1)) << 20);
            b = d4.w >> B2; sl = atomicAdd(&cur[b], 1);
            lbuf[sl] = s4.w | ((d4.w & (BN - 1)) << 20);
        } else {
            for (int j = 0; j < 4; ++j) {
                if (idx + j < E) {
                    int s = src[idx + j], d = dst[idx + j];
                    int b = d >> B2;
                    int sl = atomicAdd(&cur[b], 1);
                    lbuf[sl] = s | ((d & (BN - 1)) << 20);
                }
            }
        }
    }
    __syncthreads();
    // coalesced copy-out via binary search in lbase2
    int total = totalSh;
    for (int idx = tid; idx < total; idx += NT) {
        int lo = 0, hi = NBMAX - 1;
        while (lo < hi) {
            int mid = (lo + hi + 1) >> 1;
            if (lbase2[mid] <= idx) lo = mid; else hi = mid - 1;
        }
        pairs[gpos[lo] + (idx - lbase2[lo])] = lbuf[idx];
    }
}

// ---------- chunk range helper (inlined manually in each kernel) ----------
//   b = blockIdx.x / P, c = blockIdx.x % P; range multiple-of-4 aligned.

// ========== prep chunks: per-bucket LDS degree count -> global deg ==========
__global__ void __launch_bounds__(NT)
k_prep(const int* __restrict__ pairs, const int* __restrict__ gbase,
       int* __restrict__ deg, int N) {
    __shared__ int cnt[BN];
    int b = blockIdx.x / P, c = blockIdx.x % P;
    int tid = threadIdx.x;
    int eBeg = gbase[b], eEnd = gbase[b + 1];
    int len = eEnd - eBeg;
    int cl = (((len + P - 1) / P) + 3) & ~3;
    int s0 = eBeg + c * cl;
    int s1 = min(s0 + cl, eEnd);
    for (int l = tid; l < BN; l += NT) cnt[l] = 0;
    __syncthreads();
    for (int idx = s0 + (tid << 2); idx < s1; idx += NT * 4) {
        int4 v4 = *(const int4*)(pairs + idx);
        if (v4.x >= 0) atomicAdd(&cnt[((unsigned)v4.x) >> 20], 1);
        if (v4.y >= 0) atomicAdd(&cnt[((unsigned)v4.y) >> 20], 1);
        if (v4.z >= 0) atomicAdd(&cnt[((unsigned)v4.z) >> 20], 1);
        if (v4.w >= 0) atomicAdd(&cnt[((unsigned)v4.w) >> 20], 1);
    }
    __syncthreads();
    int base = b << B2;
    for (int j = tid; j < BN; j += NT) {
        int i = base + j;
        if (i < N && cnt[j]) atomicAdd(deg + i, cnt[j]);
    }
}

// ===== node1: dinv, y16 = half2(x*dinv); init layer1 acc with self-loop =====
__global__ void k_node1(const float2* __restrict__ x, const int* __restrict__ deg,
                        float* __restrict__ dinv, __half2* __restrict__ y16,
                        float* __restrict__ acc1a, float* __restrict__ acc1b, int N) {
    int i = blockIdx.x * blockDim.x + threadIdx.x;
    if (i >= N) return;
    float di = rsqrtf((float)(deg[i] + 1));
    dinv[i] = di;
    float2 xi = x[i];
    float ya = xi.x * di, yb = xi.y * di;
    y16[i] = __floats2half2_rn(ya, yb);
    acc1a[i] = ya;                 // self loop fp32
    acc1b[i] = yb;
}

// ========== layer1 agg chunks: LDS fp32 acc -> global atomic flush ==========
__global__ void __launch_bounds__(NT)
k_bagg1(const int* __restrict__ pairs, const int* __restrict__ gbase,
        const __half2* __restrict__ y16,
        float* __restrict__ acc1a, float* __restrict__ acc1b, int N) {
    __shared__ float a0[BN], a1[BN];
    int b = blockIdx.x / P, c = blockIdx.x % P;
    int tid = threadIdx.x;
    int eBeg = gbase[b], eEnd = gbase[b + 1];
    int len = eEnd - eBeg;
    int cl = (((len + P - 1) / P) + 3) & ~3;
    int s0 = eBeg + c * cl;
    int s1 = min(s0 + cl, eEnd);
    for (int l = tid; l < BN; l += NT) { a0[l] = 0.f; a1[l] = 0.f; }
    __syncthreads();
    for (int idx = s0 + (tid << 2); idx < s1; idx += NT * 4) {
        int4 v4 = *(const int4*)(pairs + idx);
        if (v4.x >= 0) {
            float2 f = __half22float2(y16[v4.x & 0xFFFFF]);
            int dl = ((unsigned)v4.x) >> 20;
            atomicAdd(&a0[dl], f.x); atomicAdd(&a1[dl], f.y);
        }
        if (v4.y >= 0) {
            float2 f = __half22float2(y16[v4.y & 0xFFFFF]);
            int dl = ((unsigned)v4.y) >> 20;
            atomicAdd(&a0[dl], f.x); atomicAdd(&a1[dl], f.y);
        }
        if (v4.z >= 0) {
            float2 f = __half22float2(y16[v4.z & 0xFFFFF]);
            int dl = ((unsigned)v4.z) >> 20;
            atomicAdd(&a0[dl], f.x); atomicAdd(&a1[dl], f.y);
        }
        if (v4.w >= 0) {
            float2 f = __half22float2(y16[v4.w & 0xFFFFF]);
            int dl = ((unsigned)v4.w) >> 20;
            atomicAdd(&a0[dl], f.x); atomicAdd(&a1[dl], f.y);
        }
    }
    __syncthreads();
    int base = b << B2;
    for (int j = tid; j < BN; j += NT) {
        int i = base + j;
        if (i >= N) continue;
        float v0 = a0[j], v1 = a1[j];
        if (v0 == 0.f && v1 == 0.f) continue;
        unsafeAtomicAdd(acc1a + i, v0);
        unsafeAtomicAdd(acc1b + i, v1);
    }
}

// ==== node2: layer1 epilogue (W1/relu/W2) -> hp01/h2; init layer2 acc ====
__global__ void k_node2(const float* __restrict__ acc1a, const float* __restrict__ acc1b,
                        const float* __restrict__ dinv,
                        const float* __restrict__ W1, const float* __restrict__ b1,
                        const float* __restrict__ W2,
                        __half2* __restrict__ hp01, __half* __restrict__ h2,
                        float* __restrict__ acc2a0, float* __restrict__ acc2a1,
                        float* __restrict__ acc2b, int N) {
    int i = blockIdx.x * blockDim.x + threadIdx.x;
    if (i >= N) return;
    float di = dinv[i];
    float ay0 = acc1a[i], ay1 = acc1b[i];
    float o0 = fmaxf(di * (ay0 * W1[0] + ay1 * W1[4]) + b1[0], 0.f);
    float o1 = fmaxf(di * (ay0 * W1[1] + ay1 * W1[5]) + b1[1], 0.f);
    float o2 = fmaxf(di * (ay0 * W1[2] + ay1 * W1[6]) + b1[2], 0.f);
    float o3 = fmaxf(di * (ay0 * W1[3] + ay1 * W1[7]) + b1[3], 0.f);
    float h0 = (o0 * W2[0] + o1 * W2[3] + o2 * W2[6] + o3 * W2[9])  * di;
    float h1 = (o0 * W2[1] + o1 * W2[4] + o2 * W2[7] + o3 * W2[10]) * di;
    float hv2 = (o0 * W2[2] + o1 * W2[5] + o2 * W2[8] + o3 * W2[11]) * di;
    hp01[i] = __floats2half2_rn(h0, h1);
    h2[i] = __float2half_rn(hv2);
    acc2a0[i] = h0;                // self loop fp32
    acc2a1[i] = h1;
    acc2b[i] = hv2;
}

// ========== layer2 agg chunks, channels 0,1 ==========
__global__ void __launch_bounds__(NT)
k_bagg2a(const int* __restrict__ pairs, const int* __restrict__ gbase,
         const __half2* __restrict__ hp01,
         float* __restrict__ acc2a0, float* __restrict__ acc2a1, int N) {
    __shared__ float a0[BN], a1[BN];
    int b = blockIdx.x / P, c = blockIdx.x % P;
    int tid = threadIdx.x;
    int eBeg = gbase[b], eEnd = gbase[b + 1];
    int len = eEnd - eBeg;
    int cl = (((len + P - 1) / P) + 3) & ~3;
    int s0 = eBeg + c * cl;
    int s1 = min(s0 + cl, eEnd);
    for (int l = tid; l < BN; l += NT) { a0[l] = 0.f; a1[l] = 0.f; }
    __syncthreads();
    for (int idx = s0 + (tid << 2); idx < s1; idx += NT * 4) {
        int4 v4 = *(const int4*)(pairs + idx);
        if (v4.x >= 0) {
            float2 f = __half22float2(hp01[v4.x & 0xFFFFF]);
            int dl = ((unsigned)v4.x) >> 20;
            atomicAdd(&a0[dl], f.x); atomicAdd(&a1[dl], f.y);
        }
        if (v4.y >= 0) {
            float2 f = __half22float2(hp01[v4.y & 0xFFFFF]);
            int dl = ((unsigned)v4.y) >> 20;
            atomicAdd(&a0[dl], f.x); atomicAdd(&a1[dl], f.y);
        }
        if (v4.z >= 0) {
            float2 f = __half22float2(hp01[v4.z & 0xFFFFF]);
            int dl = ((unsigned)v4.z) >> 20;
            atomicAdd(&a0[dl], f.x); atomicAdd(&a1[dl], f.y);
        }
        if (v4.w >= 0) {
            float2 f = __half22float2(hp01[v4.w & 0xFFFFF]);
            int dl = ((unsigned)v4.w) >> 20;
            atomicAdd(&a0[dl], f.x); atomicAdd(&a1[dl], f.y);
        }
    }
    __syncthreads();
    int base = b << B2;
    for (int j = tid; j < BN; j += NT) {
        int i = base + j;
        if (i >= N) continue;
        float v0 = a0[j], v1 = a1[j];
        if (v0 == 0.f && v1 == 0.f) continue;
        unsafeAtomicAdd(acc2a0 + i, v0);
        unsafeAtomicAdd(acc2a1 + i, v1);
    }
}

// ========== layer2 agg chunks, channel 2 ==========
__global__ void __launch_bounds__(NT)
k_bagg2b(const int* __restrict__ pairs, const int* __restrict__ gbase,
         const __half* __restrict__ h2, float* __restrict__ acc2b, int N) {
    __shared__ float a2[BN];
    int b = blockIdx.x / P, c = blockIdx.x % P;
    int tid = threadIdx.x;
    int eBeg = gbase[b], eEnd = gbase[b + 1];
    int len = eEnd - eBeg;
    int cl = (((len + P - 1) / P) + 3) & ~3;
    int s0 = eBeg + c * cl;
    int s1 = min(s0 + cl, eEnd);
    for (int l = tid; l < BN; l += NT) a2[l] = 0.f;
    __syncthreads();
    for (int idx = s0 + (tid << 2); idx < s1; idx += NT * 4) {
        int4 v4 = *(const int4*)(pairs + idx);
        if (v4.x >= 0)
            atomicAdd(&a2[((unsigned)v4.x) >> 20], __half2float(h2[v4.x & 0xFFFFF]));
        if (v4.y >= 0)
            atomicAdd(&a2[((unsigned)v4.y) >> 20], __half2float(h2[v4.y & 0xFFFFF]));
        if (v4.z >= 0)
            atomicAdd(&a2[((unsigned)v4.z) >> 20], __half2float(h2[v4.z & 0xFFFFF]));
        if (v4.w >= 0)
            atomicAdd(&a2[((unsigned)v4.w) >> 20], __half2float(h2[v4.w & 0xFFFFF]));
    }
    __syncthreads();
    int base = b << B2;
    for (int j = tid; j < BN; j += NT) {
        int i = base + j;
        if (i >= N) continue;
        float v = a2[j];
        if (v == 0.f) continue;
        unsafeAtomicAdd(acc2b + i, v);
    }
}

// ========== node3: sigmoid + MLP head -> out ==========
__global__ void k_node3(const float* __restrict__ acc2a0, const float* __restrict__ acc2a1,
                        const float* __restrict__ acc2b, const float* __restrict__ dinv,
                        const float* __restrict__ b2,
                        const float* __restrict__ W3, const float* __restrict__ b3,
                        const float* __restrict__ W4, const float* __restrict__ b4,
                        const float* __restrict__ W5, const float* __restrict__ b5,
                        float* __restrict__ out, int N) {
    int i = blockIdx.x * blockDim.x + threadIdx.x;
    if (i >= N) return;
    float di = dinv[i];
    float z0 = di * acc2a0[i] + b2[0];
    float z1 = di * acc2a1[i] + b2[1];
    float z2 = di * acc2b[i]  + b2[2];
    float g0 = 1.f / (1.f + expf(-z0));
    float g1 = 1.f / (1.f + expf(-z1));
    float g2 = 1.f / (1.f + expf(-z2));
    float t0 = fmaxf(g0 * W3[0] + g1 * W3[4] + g2 * W3[8]  + b3[0], 0.f);
    float t1 = fmaxf(g0 * W3[1] + g1 * W3[5] + g2 * W3[9]  + b3[1], 0.f);
    float t2 = fmaxf(g0 * W3[2] + g1 * W3[6] + g2 * W3[10] + b3[2], 0.f);
    float t3 = fmaxf(g0 * W3[3] + g1 * W3[7] + g2 * W3[11] + b3[3], 0.f);
    float u0 = fmaxf(t0 * W4[0] + t1 * W4[3] + t2 * W4[6] + t3 * W4[9]  + b4[0], 0.f);
    float u1 = fmaxf(t0 * W4[1] + t1 * W4[4] + t2 * W4[7] + t3 * W4[10] + b4[1], 0.f);
    float u2 = fmaxf(t0 * W4[2] + t1 * W4[5] + t2 * W4[8] + t3 * W4[11] + b4[2], 0.f);
    out[i] = u0 * W5[0] + u1 * W5[1] + u2 * W5[2] + b5[0];
}

// ================= fallback path (round-2 global CSR, fp32) =================
__global__ void k_deg(const int* __restrict__ dst, int* __restrict__ deg, int E) {
    int e = blockIdx.x * blockDim.x + threadIdx.x;
    if (e < E) atomicAdd(deg + dst[e], 1);
}
__global__ void k_scan1(const int* __restrict__ deg, int* __restrict__ row,
                        int* __restrict__ bsum, int N) {
    __shared__ int lds[NT];
    int base = blockIdx.x * SCAN_E + threadIdx.x * 4;
    int d0 = 0, d1 = 0, d2 = 0, d3 = 0;
    if (base + 3 < N) {
        int4 v = *(const int4*)(deg + base);
        d0 = v.x; d1 = v.y; d2 = v.z; d3 = v.w;
    } else {
        if (base     < N) d0 = deg[base];
        if (base + 1 < N) d1 = deg[base + 1];
        if (base + 2 < N) d2 = deg[base + 2];
        if (base + 3 < N) d3 = deg[base + 3];
    }
    int t = d0 + d1 + d2 + d3;
    lds[threadIdx.x] = t;
    __syncthreads();
    for (int off = 1; off < NT; off <<= 1) {
        int v = (threadIdx.x >= off) ? lds[threadIdx.x - off] : 0;
        __syncthreads();
        lds[threadIdx.x] += v;
        __syncthreads();
    }
    int excl = lds[threadIdx.x] - t;
    if (threadIdx.x == NT - 1) bsum[blockIdx.x] = lds[NT - 1];
    if (base     < N) row[base]     = excl;
    if (base + 1 < N) row[base + 1] = excl + d0;
    if (base + 2 < N) row[base + 2] = excl + d0 + d1;
    if (base + 3 < N) row[base + 3] = excl + d0 + d1 + d2;
}
__global__ void k_scan2(int* __restrict__ bsum, int M) {
    __shared__ int lds[NT];
    int base = threadIdx.x * 4;
    int d0 = 0, d1 = 0, d2 = 0, d3 = 0;
    if (base     < M) d0 = bsum[base];
    if (base + 1 < M) d1 = bsum[base + 1];
    if (base + 2 < M) d2 = bsum[base + 2];
    if (base + 3 < M) d3 = bsum[base + 3];
    int t = d0 + d1 + d2 + d3;
    lds[threadIdx.x] = t;
    __syncthreads();
    for (int off = 1; off < NT; off <<= 1) {
        int v = (threadIdx.x >= off) ? lds[threadIdx.x - off] : 0;
        __syncthreads();
        lds[threadIdx.x] += v;
        __syncthreads();
    }
    int excl = lds[threadIdx.x] - t;
    if (base     < M) bsum[base]     = excl;
    if (base + 1 < M) bsum[base + 1] = excl + d0;
    if (base + 2 < M) bsum[base + 2] = excl + d0 + d1;
    if (base + 3 < M) bsum[base + 3] = excl + d0 + d1 + d2;
}
__global__ void k_scan3(int* __restrict__ row, const int* __restrict__ bsum, int N) {
    int base = blockIdx.x * SCAN_E + threadIdx.x * 4;
    int add = bsum[blockIdx.x];
    if (base + 3 < N) {
        int4 v = *(int4*)(row + base);
        v.x += add; v.y += add; v.z += add; v.w += add;
        *(int4*)(row + base) = v;
    } else {
        if (base     < N) row[base]     += add;
        if (base + 1 < N) row[base + 1] += add;
        if (base + 2 < N) row[base + 2] += add;
    }
}
__global__ void k_scatter(const int* __restrict__ src, const int* __restrict__ dst,
                          int* __restrict__ row, int* __restrict__ ss, int E) {
    int e = blockIdx.x * blockDim.x + threadIdx.x;
    if (e >= E) return;
    int s = src[e], d = dst[e];
    int slot = atomicAdd(row + d, 1);
    ss[slot] = s;
}
__global__ void k_node1_fb(const float2* __restrict__ x, const int* __restrict__ deg,
                           const float* __restrict__ W1,
                           float* __restrict__ dinv, float4* __restrict__ hp, int N) {
    int i = blockIdx.x * blockDim.x + threadIdx.x;
    if (i >= N) return;
    float2 xi = x[i];
    float di = rsqrtf((float)(deg[i] + 1));
    dinv[i] = di;
    float4 h;
    h.x = (xi.x * W1[0] + xi.y * W1[4]) * di;
    h.y = (xi.x * W1[1] + xi.y * W1[5]) * di;
    h.z = (xi.x * W1[2] + xi.y * W1[6]) * di;
    h.w = (xi.x * W1[3] + xi.y * W1[7]) * di;
    hp[i] = h;
}
__global__ void k_aggf1_fb(const int* __restrict__ row, const int* __restrict__ ss,
                           const float4* __restrict__ hp1, const float* __restrict__ dinv,
                           const float* __restrict__ b1, const float* __restrict__ W2,
                           float4* __restrict__ hp2, int N) {
    int i = blockIdx.x * blockDim.x + threadIdx.x;
    if (i >= N) return;
    int beg = (i == 0) ? 0 : row[i - 1];
    int end = row[i];
    float4 a = hp1[i];
    for (int e = beg; e < end; ++e) {
        float4 ha = hp1[ss[e]];
        a.x += ha.x; a.y += ha.y; a.z += ha.z; a.w += ha.w;
    }
    float di = dinv[i];
    float o0 = fmaxf(di * a.x + b1[0], 0.f);
    float o1 = fmaxf(di * a.y + b1[1], 0.f);
    float o2 = fmaxf(di * a.z + b1[2], 0.f);
    float o3 = fmaxf(di * a.w + b1[3], 0.f);
    float4 h;
    h.x = (o0 * W2[0] + o1 * W2[3] + o2 * W2[6] + o3 * W2[9])  * di;
    h.y = (o0 * W2[1] + o1 * W2[4] + o2 * W2[7] + o3 * W2[10]) * di;
    h.z = (o0 * W2[2] + o1 * W2[5] + o2 * W2[8] + o3 * W2[11]) * di;
    h.w = 0.f;
    hp2[i] = h;
}
__global__ void k_aggf2_fb(const int* __restrict__ row, const int* __restrict__ ss,
                           const float4* __restrict__ hp2, const float* __restrict__ dinv,
                           const float* __restrict__ b2,
                           const float* __restrict__ W3, const float* __restrict__ b3,
                           const float* __restrict__ W4, const float* __restrict__ b4,
                           const float* __restrict__ W5, const float* __restrict__ b5,
                           float* __restrict__ out, int N) {
    int i = blockIdx.x * blockDim.x + threadIdx.x;
    if (i >= N) return;
    int beg = (i == 0) ? 0 : row[i - 1];
    int end = row[i];
    float4 a = hp2[i];
    for (int e = beg; e < end; ++e) {
        float4 ha = hp2[ss[e]];
        a.x += ha.x; a.y += ha.y; a.z += ha.z;
    }
    float di = dinv[i];
    float z0 = di * a.x + b2[0];
    float z1 = di * a.y + b2[1];
    float z2 = di * a.z + b2[2];
    float g0 = 1.f / (1.f + expf(-z0));
    float g1 = 1.f / (1.f + expf(-z1));
    float g2 = 1.f / (1.f + expf(-z2));
    float t0 = fmaxf(g0 * W3[0] + g1 * W3[4] + g2 * W3[8]  + b3[0], 0.f);
    float t1 = fmaxf(g0 * W3[1] + g1 * W3[5] + g2 * W3[9]  + b3[1], 0.f);
    float t2 = fmaxf(g0 * W3[2] + g1 * W3[6] + g2 * W3[10] + b3[2], 0.f);
    float t3 = fmaxf(g0 * W3[3] + g1 * W3[7] + g2 * W3[11] + b3[3], 0.f);
    float u0 = fmaxf(t0 * W4[0] + t1 * W4[3] + t2 * W4[6] + t3 * W4[9]  + b4[0], 0.f);
    float u1 = fmaxf(t0 * W4[1] + t1 * W4[4] + t2 * W4[7] + t3 * W4[10] + b4[1], 0.f);
    float u2 = fmaxf(t0 * W4[2] + t1 * W4[5] + t2 * W4[8] + t3 * W4[11] + b4[2], 0.f);
    out[i] = u0 * W5[0] + u1 * W5[1] + u2 * W5[2] + b5[0];
}

extern "C" void kernel_launch(void* const* d_in, const int* in_sizes, int n_in,
                              void* d_out, int out_size, void* d_ws, size_t ws_size,
                              hipStream_t stream) {
    const float* x  = (const float*)d_in[0];
    const int*   ei = (const int*)d_in[1];
    const float* W1 = (const float*)d_in[2];
    const float* b1 = (const float*)d_in[3];
    const float* W2 = (const float*)d_in[4];
    const float* b2 = (const float*)d_in[5];
    const float* W3 = (const float*)d_in[6];
    const float* b3 = (const float*)d_in[7];
    const float* W4 = (const float*)d_in[8];
    const float* b4 = (const float*)d_in[9];
    const float* W5 = (const float*)d_in[10];
    const float* b5 = (const float*)d_in[11];

    const int N = in_sizes[0] / 2;
    const int E = in_sizes[1] / 2;
    const int* src = ei;
    const int* dst = ei + E;

    const int gbN = (N + NT - 1) / NT;
    const int gbE = (E + NT - 1) / NT;
    const int tiles = (E + TILE - 1) / TILE;
    const int NB = (N + BN - 1) >> B2;

    char* ws = (char*)d_ws;

    // -------- primary layout --------
    size_t szPairs = (size_t)(E + 4 * NBMAX) * 4;
    size_t offDeg  = (szPairs + 15) & ~(size_t)15;
    size_t offDinv = offDeg  + (size_t)N * 4;
    size_t offY16  = offDinv + (size_t)N * 4;
    size_t offA1a  = offY16  + (size_t)N * 4;
    size_t offA1b  = offA1a  + (size_t)N * 4;
    size_t offH01  = offA1b  + (size_t)N * 4;
    size_t offH2   = offH01  + (size_t)N * 4;
    size_t offA2a0 = (offH2 + (size_t)N * 2 + 15) & ~(size_t)15;
    size_t offA2a1 = offA2a0 + (size_t)N * 4;
    size_t offA2b  = offA2a1 + (size_t)N * 4;
    size_t offHist = offA2b  + (size_t)N * 4;
    size_t need1   = offHist + 3 * (NBMAX + 1) * 4 + 64;

    if (N <= (1 << 20) && NB <= NBMAX && ws_size >= need1) {
        int*     pairs  = (int*)ws;
        int*     deg    = (int*)(ws + offDeg);
        float*   dinv   = (float*)(ws + offDinv);
        __half2* y16    = (__half2*)(ws + offY16);
        float*   acc1a  = (float*)(ws + offA1a);
        float*   acc1b  = (float*)(ws + offA1b);
        __half2* hp01   = (__half2*)(ws + offH01);
        __half*  h2     = (__half*)(ws + offH2);
        float*   acc2a0 = (float*)(ws + offA2a0);
        float*   acc2a1 = (float*)(ws + offA2a1);
        float*   acc2b  = (float*)(ws + offA2b);
        int*     ghist  = (int*)(ws + offHist);
        int*     gbase  = ghist + (NBMAX + 1);
        int*     gcur   = gbase + (NBMAX + 1);

        hipMemsetAsync(ghist, 0, (NBMAX + 1) * 4, stream);
        hipMemsetAsync(deg, 0, (size_t)N * 4, stream);
        k_binhist    <<<tiles, NT, 0, stream>>>(dst, ghist, E);
        k_scanbuckets<<<1, NBMAX, 0, stream>>>(ghist, gbase, gcur, pairs, NB);
        k_binscatter <<<tiles, NT, 0, stream>>>(src, dst, gcur, pairs, E, NB);
        k_prep       <<<NB * P, NT, 0, stream>>>(pairs, gbase, deg, N);
        k_node1      <<<gbN, NT, 0, stream>>>((const float2*)x, deg, dinv, y16,
                                              acc1a, acc1b, N);
        k_bagg1      <<<NB * P, NT, 0, stream>>>(pairs, gbase, y16, acc1a, acc1b, N);
        k_node2      <<<gbN, NT, 0, stream>>>(acc1a, acc1b, dinv, W1, b1, W2,
                                              hp01, h2, acc2a0, acc2a1, acc2b, N);
        k_bagg2a     <<<NB * P, NT, 0, stream>>>(pairs, gbase, hp01, acc2a0, acc2a1, N);
        k_bagg2b     <<<NB * P, NT, 0, stream>>>(pairs, gbase, h2, acc2b, N);
        k_node3      <<<gbN, NT, 0, stream>>>(acc2a0, acc2a1, acc2b, dinv, b2,
                                              W3, b3, W4, b4, W5, b5,
                                              (float*)d_out, N);
        return;
    }

    // -------- fallback: global counting-sort CSR (fp32) --------
    const int nScanBlocks = (N + SCAN_E - 1) / SCAN_E;
    size_t need2 = (size_t)N * 44 + (size_t)E * 4 + (size_t)nScanBlocks * 4 + 256;
    if (ws_size >= need2 && nScanBlocks <= NT * 4) {
        float4* hp1  = (float4*)ws;
        float4* hp2  = (float4*)(ws + (size_t)N * 16);
        int*    ss   = (int*)   (ws + (size_t)N * 32);
        int*    deg  = (int*)   (ws + (size_t)N * 32 + (size_t)E * 4);
        int*    row  = (int*)   (ws + (size_t)N * 36 + (size_t)E * 4);
        float*  dinv = (float*) (ws + (size_t)N * 40 + (size_t)E * 4);
        int*    bsum = (int*)   (ws + (size_t)N * 44 + (size_t)E * 4);

        hipMemsetAsync(deg, 0, (size_t)N * 4, stream);
        k_deg     <<<gbE, NT, 0, stream>>>(dst, deg, E);
        k_scan1   <<<nScanBlocks, NT, 0, stream>>>(deg, row, bsum, N);
        k_scan2   <<<1, NT, 0, stream>>>(bsum, nScanBlocks);
        k_scan3   <<<nScanBlocks, NT, 0, stream>>>(row, bsum, N);
        k_node1_fb<<<gbN, NT, 0, stream>>>((const float2*)x, deg, W1, dinv, hp1, N);
        k_scatter <<<gbE, NT, 0, stream>>>(src, dst, row, ss, E);
        k_aggf1_fb<<<gbN, NT, 0, stream>>>(row, ss, hp1, dinv, b1, W2, hp2, N);
        k_aggf2_fb<<<gbN, NT, 0, stream>>>(row, ss, hp2, dinv, b2, W3, b3, W4, b4,
                                           W5, b5, (float*)d_out, N);
    }
}